// Round 6
// baseline (954.728 us; speedup 1.0000x reference)
//
#include <hip/hip_runtime.h>
#include <math.h>

#define N_NODES 100000
#define N_EDGES 1000000
#define IN_F 128
#define HID 64
#define OUT_F 64
#define NLAYERS 4
#define ALPHA 0.1f
#define BN_EPS 1e-5f

#define SCAN_BLK 256
#define NSCAN_BLOCKS ((N_NODES + SCAN_BLK - 1) / SCAN_BLK)   // 391

// ---- workspace layout (bytes) ----
// Feature buffers first: fp32 rows 256B-aligned, bf16 gather rows 128B-aligned.
static const size_t OFF_X0       = 0;                       // N*64*4 = 25600000
static const size_t OFF_HA       = 25600000;
static const size_t OFF_HB       = 51200000;
static const size_t OFF_GB       = 76800000;                // N*64*2 = 12800000 (bf16, dinv-prescaled)
static const size_t OFF_SORTED   = 89600000;                // E*4 = 4000000
static const size_t OFF_CNT      = 93600000;                // N*4
static const size_t OFF_STATS    = 94000000;                // 512*4 = 2048
static const size_t OFF_DINV     = 94002048;                // N*4
static const size_t OFF_ROWSTART = 94402048;                // (N+1)*4 -> 400016
static const size_t OFF_CURSOR   = 94802064;                // N*4
static const size_t OFF_BSUM     = 95202064;                // 391*4 -> pad 2048; end = 95204112
static const size_t ZERO_OFF     = OFF_CNT;                 // cnt+stats contiguous
static const size_t ZERO_BYTES   = 402048;

__device__ __forceinline__ unsigned short f2b(float f) {
    unsigned int u = __float_as_uint(f);
    u += 0x7FFFu + ((u >> 16) & 1u);        // round-to-nearest-even
    return (unsigned short)(u >> 16);
}
__device__ __forceinline__ float b2f(unsigned short h) {
    return __uint_as_float(((unsigned int)h) << 16);
}

__global__ void hist_kernel(const int* __restrict__ row, int* __restrict__ cnt, int e) {
    int i = blockIdx.x * blockDim.x + threadIdx.x;
    if (i < e) atomicAdd(&cnt[row[i]], 1);
}

__global__ void dinv_kernel(const int* __restrict__ cnt, float* __restrict__ dinv, int n) {
    int i = blockIdx.x * blockDim.x + threadIdx.x;
    if (i < n) {
        int d = cnt[i];
        dinv[i] = d > 0 ? rsqrtf((float)d) : 0.0f;
    }
}

// ---- 3-phase multi-block exclusive scan of cnt -> rs[0..n], cur ----
__global__ __launch_bounds__(SCAN_BLK) void blocksum_kernel(const int* __restrict__ cnt,
        int* __restrict__ bsum, int n) {
    __shared__ int red[SCAN_BLK / 64];
    int i = blockIdx.x * SCAN_BLK + threadIdx.x;
    int v = (i < n) ? cnt[i] : 0;
#pragma unroll
    for (int off = 32; off > 0; off >>= 1) v += __shfl_down(v, off, 64);
    if ((threadIdx.x & 63) == 0) red[threadIdx.x >> 6] = v;
    __syncthreads();
    if (threadIdx.x == 0) {
        int s = 0;
#pragma unroll
        for (int j = 0; j < SCAN_BLK / 64; ++j) s += red[j];
        bsum[blockIdx.x] = s;
    }
}

__global__ __launch_bounds__(512) void scan_bsum_kernel(int* __restrict__ bsum, int nb) {
    __shared__ int lds[512];
    int t = threadIdx.x;
    lds[t] = (t < nb) ? bsum[t] : 0;
    __syncthreads();
    for (int off = 1; off < 512; off <<= 1) {
        int v = lds[t];
        int add = (t >= off) ? lds[t - off] : 0;
        __syncthreads();
        lds[t] = v + add;
        __syncthreads();
    }
    if (t < nb) bsum[t] = (t == 0) ? 0 : lds[t - 1];
}

__global__ __launch_bounds__(SCAN_BLK) void scan_write_kernel(const int* __restrict__ cnt,
        const int* __restrict__ bsum, int* __restrict__ rs, int* __restrict__ cur, int n) {
    __shared__ int lds[SCAN_BLK];
    int t = threadIdx.x;
    int i = blockIdx.x * SCAN_BLK + t;
    int c = (i < n) ? cnt[i] : 0;
    lds[t] = c;
    __syncthreads();
    for (int off = 1; off < SCAN_BLK; off <<= 1) {
        int v = lds[t];
        int add = (t >= off) ? lds[t - off] : 0;
        __syncthreads();
        lds[t] = v + add;
        __syncthreads();
    }
    if (i < n) {
        int excl = bsum[blockIdx.x] + lds[t] - c;
        rs[i] = excl;
        cur[i] = excl;
        if (i == n - 1) rs[n] = excl + c;
    }
}

__global__ void scatter_kernel(const int* __restrict__ edges, int* __restrict__ cur,
                               int* __restrict__ scol, int e) {
    int i = blockIdx.x * blockDim.x + threadIdx.x;
    if (i < e) {
        int r = edges[i];
        int c = edges[e + i];
        int pos = atomicAdd(&cur[r], 1);
        scol[pos] = c;
    }
}

// x0 = relu(x @ W0 + b0) + bf16 gather twin, split-K across wave pairs:
// half=0 holds W0[k<64][:], half=1 holds W0[k>=64][:] (64 regs each -> no spill
// under the compiler's hard 128-VGPR ceiling seen in R4/R5). Partials meet in
// LDS (double-buffered, 1 barrier/iter). Block-uniform loop bound (no deadlock).
__global__ __launch_bounds__(256, 2) void fc0_kernel(const float* __restrict__ x,
        const float* __restrict__ W0, const float* __restrict__ b0,
        const float* __restrict__ dinv, float* __restrict__ out,
        unsigned short* __restrict__ g, int n) {
    __shared__ float part[2][4][64];
    int wave = threadIdx.x >> 6, lane = threadIdx.x & 63;
    int pairid = wave >> 1;      // row slot within the block (0 or 1)
    int half = wave & 1;         // which K-half this wave owns
    float w[64];
#pragma unroll
    for (int k = 0; k < 64; ++k) w[k] = W0[(half * 64 + k) * HID + lane];
    float bias = (half == 0) ? b0[lane] : 0.f;
    int nw = gridDim.x * 2;
    int pb = 0;
    for (int base = blockIdx.x * 2; base < n; base += nw, pb ^= 1) {
        int r = base + pairid;
        bool active = r < n;
        float xv = active ? x[(size_t)r * IN_F + half * 64 + lane] : 0.f;
        float acc = bias;
#pragma unroll
        for (int k = 0; k < 64; ++k) acc += __shfl(xv, k, 64) * w[k];
        part[pb][wave][lane] = acc;
        __syncthreads();
        if (half == 0 && active) {
            float v = acc + part[pb][wave + 1][lane];
            v = v > 0.f ? v : 0.f;
            out[(size_t)r * HID + lane] = v;
            g[(size_t)r * HID + lane] = f2b(dinv[r] * v);
        }
    }
}

// SPMM from bf16 dinv-prescaled gather buffer: one 128B line per edge,
// no per-edge dinv load. Predicated batch-8 for MLP (lean regs, no spill).
__global__ __launch_bounds__(256, 8) void spmm_kernel(const unsigned short* __restrict__ g,
        const float* __restrict__ x0, const float* __restrict__ dinv,
        const int* __restrict__ rs, const int* __restrict__ scol,
        float* __restrict__ sout, int n) {
    int wave = threadIdx.x >> 6, lane = threadIdx.x & 63;
    int nw = gridDim.x * 4;
    for (int r = blockIdx.x * 4 + wave; r < n; r += nw) {
        int e0 = rs[r], e1 = rs[r + 1];
        float agg = 0.f;
        for (int e = e0; e < e1; e += 8) {
            int cc[8];
            float vv[8];
#pragma unroll
            for (int j = 0; j < 8; ++j) {
                int ee = e + j;
                cc[j] = scol[ee < e1 ? ee : e1 - 1];
            }
#pragma unroll
            for (int j = 0; j < 8; ++j) {
                float v = b2f(g[(size_t)cc[j] * HID + lane]);
                vv[j] = (e + j < e1) ? v : 0.f;
            }
            agg += ((vv[0] + vv[1]) + (vv[2] + vv[3])) +
                   ((vv[4] + vv[5]) + (vv[6] + vv[7]));
        }
        sout[(size_t)r * HID + lane] =
            (1.f - ALPHA) * dinv[r] * agg + ALPHA * x0[(size_t)r * HID + lane];
    }
}

// h = (1-beta)*s + beta*(s@cw), in place; per-channel sum/sumsq block-reduced.
__global__ __launch_bounds__(256, 2) void dense_stats_kernel(float* __restrict__ s_in,
        const float* __restrict__ cw, float* __restrict__ stats, float beta, int n) {
    __shared__ float red[4 * 128];
    int wave = threadIdx.x >> 6, lane = threadIdx.x & 63;
    float w[HID];
#pragma unroll
    for (int k = 0; k < HID; ++k) w[k] = cw[k * HID + lane];
    float lsum = 0.f, lsq = 0.f;
    int nw = gridDim.x * 4;
    for (int r = blockIdx.x * 4 + wave; r < n; r += nw) {
        float sv = s_in[(size_t)r * HID + lane];
        float m = 0.f;
#pragma unroll
        for (int k = 0; k < HID; ++k) m += __shfl(sv, k, 64) * w[k];
        float hv = (1.f - beta) * sv + beta * m;
        s_in[(size_t)r * HID + lane] = hv;
        lsum += hv; lsq += hv * hv;
    }
    red[wave * 128 + lane] = lsum;
    red[wave * 128 + 64 + lane] = lsq;
    __syncthreads();
    if (threadIdx.x < 128) {
        int t = threadIdx.x;
        float v = red[t] + red[128 + t] + red[256 + t] + red[384 + t];
        atomicAdd(&stats[t], v);
    }
}

// BN + residual + relu in place; also writes next-layer gather twin g = bf16(dinv*out)
__global__ void layerB_kernel(float4* __restrict__ h, const float4* __restrict__ xprev,
        const float* __restrict__ stats, const float* __restrict__ gamma,
        const float* __restrict__ bnb, const float* __restrict__ dinv,
        ushort4* __restrict__ g, int total4) {
    int i = blockIdx.x * blockDim.x + threadIdx.x;
    if (i >= total4) return;
    int fb = (i & 15) * 4;
    int row = i >> 4;
    float dr = dinv[row];
    float4 hv = h[i];
    float4 xp = xprev[i];
    float o[4];
    float hin[4] = { hv.x, hv.y, hv.z, hv.w };
    float xin[4] = { xp.x, xp.y, xp.z, xp.w };
#pragma unroll
    for (int j = 0; j < 4; ++j) {
        int f = fb + j;
        float mu = stats[f] * (1.0f / N_NODES);
        float var = stats[64 + f] * (1.0f / N_NODES) - mu * mu;
        if (var < 0.f) var = 0.f;
        float inv = rsqrtf(var + BN_EPS);
        float v = (hin[j] - mu) * inv * gamma[f] + bnb[f] + xin[j];
        o[j] = v > 0.f ? v : 0.f;
    }
    h[i] = make_float4(o[0], o[1], o[2], o[3]);
    ushort4 gu;
    gu.x = f2b(dr * o[0]); gu.y = f2b(dr * o[1]);
    gu.z = f2b(dr * o[2]); gu.w = f2b(dr * o[3]);
    g[i] = gu;
}

// out = x @ W1 + b1
__global__ __launch_bounds__(256, 2) void final_kernel(const float* __restrict__ xcur,
        const float* __restrict__ W1, const float* __restrict__ b1,
        float* __restrict__ out, int n) {
    int wave = threadIdx.x >> 6, lane = threadIdx.x & 63;
    float w[HID];
#pragma unroll
    for (int k = 0; k < HID; ++k) w[k] = W1[k * OUT_F + lane];
    float bias = b1[lane];
    int nw = gridDim.x * 4;
    for (int r = blockIdx.x * 4 + wave; r < n; r += nw) {
        float xv = xcur[(size_t)r * HID + lane];
        float acc = bias;
#pragma unroll
        for (int k = 0; k < HID; ++k) acc += __shfl(xv, k, 64) * w[k];
        out[(size_t)r * OUT_F + lane] = acc;
    }
}

extern "C" void kernel_launch(void* const* d_in, const int* in_sizes, int n_in,
                              void* d_out, int out_size, void* d_ws, size_t ws_size,
                              hipStream_t stream) {
    const float* x     = (const float*)d_in[0];
    const int*   edges = (const int*)d_in[1];
    const float* W0    = (const float*)d_in[2];
    const float* b0    = (const float*)d_in[3];
    const float* cw    = (const float*)d_in[4];
    const float* gamma = (const float*)d_in[5];
    const float* bnb   = (const float*)d_in[6];
    const float* W1    = (const float*)d_in[7];
    const float* b1    = (const float*)d_in[8];
    float* out = (float*)d_out;

    char* ws = (char*)d_ws;
    float* x0    = (float*)(ws + OFF_X0);
    float* bufA  = (float*)(ws + OFF_HA);
    float* bufB  = (float*)(ws + OFF_HB);
    unsigned short* gbuf = (unsigned short*)(ws + OFF_GB);
    int*   scol  = (int*)(ws + OFF_SORTED);
    int*   cnt   = (int*)(ws + OFF_CNT);
    float* stats = (float*)(ws + OFF_STATS);
    float* dinv  = (float*)(ws + OFF_DINV);
    int*   rs    = (int*)(ws + OFF_ROWSTART);
    int*   cur   = (int*)(ws + OFF_CURSOR);
    int*   bsum  = (int*)(ws + OFF_BSUM);

    hipMemsetAsync(ws + ZERO_OFF, 0, ZERO_BYTES, stream);
    hist_kernel<<<(N_EDGES + 255) / 256, 256, 0, stream>>>(edges, cnt, N_EDGES);
    dinv_kernel<<<(N_NODES + 255) / 256, 256, 0, stream>>>(cnt, dinv, N_NODES);
    blocksum_kernel<<<NSCAN_BLOCKS, SCAN_BLK, 0, stream>>>(cnt, bsum, N_NODES);
    scan_bsum_kernel<<<1, 512, 0, stream>>>(bsum, NSCAN_BLOCKS);
    scan_write_kernel<<<NSCAN_BLOCKS, SCAN_BLK, 0, stream>>>(cnt, bsum, rs, cur, N_NODES);
    scatter_kernel<<<(N_EDGES + 255) / 256, 256, 0, stream>>>(edges, cur, scol, N_EDGES);
    fc0_kernel<<<2048, 256, 0, stream>>>(x, W0, b0, dinv, x0, gbuf, N_NODES);

    const float* xc = x0;
    float* bufs[2] = { bufA, bufB };
    for (int i = 0; i < NLAYERS; ++i) {
        float beta = logf(0.5f / (float)(i + 1) + 1.0f);
        float* hb = bufs[i & 1];
        spmm_kernel<<<2048, 256, 0, stream>>>(gbuf, x0, dinv, rs, scol, hb, N_NODES);
        dense_stats_kernel<<<2048, 256, 0, stream>>>(hb,
                cw + (size_t)i * HID * HID, stats + i * 128, beta, N_NODES);
        layerB_kernel<<<(N_NODES * HID / 4 + 255) / 256, 256, 0, stream>>>(
                (float4*)hb, (const float4*)xc,
                stats + i * 128, gamma + i * HID, bnb + i * HID, dinv,
                (ushort4*)gbuf, N_NODES * HID / 4);
        xc = hb;
    }
    final_kernel<<<2048, 256, 0, stream>>>(xc, W1, b1, out, N_NODES);
}

// Round 7
// 948.142 us; speedup vs baseline: 1.0069x; 1.0069x over previous
//
#include <hip/hip_runtime.h>
#include <math.h>

#define N_NODES 100000
#define N_EDGES 1000000
#define IN_F 128
#define HID 64
#define OUT_F 64
#define NLAYERS 4
#define ALPHA 0.1f
#define BN_EPS 1e-5f

#define SCAN_BLK 256
#define NSCAN_BLOCKS ((N_NODES + SCAN_BLK - 1) / SCAN_BLK)   // 391

// ---- workspace layout (bytes) ----
static const size_t OFF_X0       = 0;                       // N*64*4 = 25600000
static const size_t OFF_HA       = 25600000;
static const size_t OFF_HB       = 51200000;
static const size_t OFF_GB       = 76800000;                // N*64*2 = 12800000 (bf16, dinv-prescaled)
static const size_t OFF_SORTED   = 89600000;                // E*4 = 4000000
static const size_t OFF_CNT      = 93600000;                // N*4
static const size_t OFF_STATS    = 94000000;                // 512*4 = 2048
static const size_t OFF_DINV     = 94002048;                // N*4
static const size_t OFF_ROWSTART = 94402048;                // (N+1)*4 -> 400016
static const size_t OFF_CURSOR   = 94802064;                // N*4
static const size_t OFF_BSUM     = 95202064;                // 391*4 -> pad 2048; end = 95204112
static const size_t ZERO_OFF     = OFF_CNT;
static const size_t ZERO_BYTES   = 402048;

__device__ __forceinline__ unsigned short f2b(float f) {
    unsigned int u = __float_as_uint(f);
    u += 0x7FFFu + ((u >> 16) & 1u);        // round-to-nearest-even
    return (unsigned short)(u >> 16);
}
__device__ __forceinline__ float b2f(unsigned short h) {
    return __uint_as_float(((unsigned int)h) << 16);
}

__global__ void hist_kernel(const int* __restrict__ row, int* __restrict__ cnt, int e) {
    int i = blockIdx.x * blockDim.x + threadIdx.x;
    if (i < e) atomicAdd(&cnt[row[i]], 1);
}

__global__ void dinv_kernel(const int* __restrict__ cnt, float* __restrict__ dinv, int n) {
    int i = blockIdx.x * blockDim.x + threadIdx.x;
    if (i < n) {
        int d = cnt[i];
        dinv[i] = d > 0 ? rsqrtf((float)d) : 0.0f;
    }
}

// ---- 3-phase multi-block exclusive scan of cnt -> rs[0..n], cur ----
__global__ __launch_bounds__(SCAN_BLK) void blocksum_kernel(const int* __restrict__ cnt,
        int* __restrict__ bsum, int n) {
    __shared__ int red[SCAN_BLK / 64];
    int i = blockIdx.x * SCAN_BLK + threadIdx.x;
    int v = (i < n) ? cnt[i] : 0;
#pragma unroll
    for (int off = 32; off > 0; off >>= 1) v += __shfl_down(v, off, 64);
    if ((threadIdx.x & 63) == 0) red[threadIdx.x >> 6] = v;
    __syncthreads();
    if (threadIdx.x == 0) {
        int s = 0;
#pragma unroll
        for (int j = 0; j < SCAN_BLK / 64; ++j) s += red[j];
        bsum[blockIdx.x] = s;
    }
}

__global__ __launch_bounds__(512) void scan_bsum_kernel(int* __restrict__ bsum, int nb) {
    __shared__ int lds[512];
    int t = threadIdx.x;
    lds[t] = (t < nb) ? bsum[t] : 0;
    __syncthreads();
    for (int off = 1; off < 512; off <<= 1) {
        int v = lds[t];
        int add = (t >= off) ? lds[t - off] : 0;
        __syncthreads();
        lds[t] = v + add;
        __syncthreads();
    }
    if (t < nb) bsum[t] = (t == 0) ? 0 : lds[t - 1];
}

__global__ __launch_bounds__(SCAN_BLK) void scan_write_kernel(const int* __restrict__ cnt,
        const int* __restrict__ bsum, int* __restrict__ rs, int* __restrict__ cur, int n) {
    __shared__ int lds[SCAN_BLK];
    int t = threadIdx.x;
    int i = blockIdx.x * SCAN_BLK + t;
    int c = (i < n) ? cnt[i] : 0;
    lds[t] = c;
    __syncthreads();
    for (int off = 1; off < SCAN_BLK; off <<= 1) {
        int v = lds[t];
        int add = (t >= off) ? lds[t - off] : 0;
        __syncthreads();
        lds[t] = v + add;
        __syncthreads();
    }
    if (i < n) {
        int excl = bsum[blockIdx.x] + lds[t] - c;
        rs[i] = excl;
        cur[i] = excl;
        if (i == n - 1) rs[n] = excl + c;
    }
}

__global__ void scatter_kernel(const int* __restrict__ edges, int* __restrict__ cur,
                               int* __restrict__ scol, int e) {
    int i = blockIdx.x * blockDim.x + threadIdx.x;
    if (i < e) {
        int r = edges[i];
        int c = edges[e + i];
        int pos = atomicAdd(&cur[r], 1);
        scol[pos] = c;
    }
}

// x0 = relu(x @ W0 + b0) + bf16 gather twin. Split-K across wave pairs,
// 4 rows per pair-iteration: 4 independent 256B x-loads in flight (MLP x4),
// 4 independent FMA chains (ILP x4), barrier amortized over 8 rows/block.
__global__ __launch_bounds__(256, 2) void fc0_kernel(const float* __restrict__ x,
        const float* __restrict__ W0, const float* __restrict__ b0,
        const float* __restrict__ dinv, float* __restrict__ out,
        unsigned short* __restrict__ g, int n) {
    __shared__ float part[2][4][4][64];     // [pb][wave][rowj][lane]
    int wave = threadIdx.x >> 6, lane = threadIdx.x & 63;
    int pairid = wave >> 1;      // 0 or 1: which 4-row group
    int half = wave & 1;         // which K-half this wave owns
    float w[64];
#pragma unroll
    for (int k = 0; k < 64; ++k) w[k] = W0[(half * 64 + k) * HID + lane];
    float bias = (half == 0) ? b0[lane] : 0.f;
    int stride = gridDim.x * 8;
    int pb = 0;
    for (int base = blockIdx.x * 8; base < n; base += stride, pb ^= 1) {
        int r0 = base + pairid * 4;
        float xv[4];
#pragma unroll
        for (int j = 0; j < 4; ++j) {
            int r = r0 + j;
            xv[j] = (r < n) ? x[(size_t)r * IN_F + half * 64 + lane] : 0.f;
        }
        float a0 = bias, a1 = bias, a2 = bias, a3 = bias;
#pragma unroll
        for (int k = 0; k < 64; ++k) {
            float wk = w[k];
            a0 += __shfl(xv[0], k, 64) * wk;
            a1 += __shfl(xv[1], k, 64) * wk;
            a2 += __shfl(xv[2], k, 64) * wk;
            a3 += __shfl(xv[3], k, 64) * wk;
        }
        part[pb][wave][0][lane] = a0;
        part[pb][wave][1][lane] = a1;
        part[pb][wave][2][lane] = a2;
        part[pb][wave][3][lane] = a3;
        __syncthreads();
        if (half == 0) {
            float acc[4] = { a0, a1, a2, a3 };
#pragma unroll
            for (int j = 0; j < 4; ++j) {
                int r = r0 + j;
                if (r < n) {
                    float v = acc[j] + part[pb][wave + 1][j][lane];
                    v = v > 0.f ? v : 0.f;
                    out[(size_t)r * HID + lane] = v;
                    g[(size_t)r * HID + lane] = f2b(dinv[r] * v);
                }
            }
        }
    }
}

// SPMM from bf16 dinv-prescaled gather buffer: one 128B line per edge.
__global__ __launch_bounds__(256, 8) void spmm_kernel(const unsigned short* __restrict__ g,
        const float* __restrict__ x0, const float* __restrict__ dinv,
        const int* __restrict__ rs, const int* __restrict__ scol,
        float* __restrict__ sout, int n) {
    int wave = threadIdx.x >> 6, lane = threadIdx.x & 63;
    int nw = gridDim.x * 4;
    for (int r = blockIdx.x * 4 + wave; r < n; r += nw) {
        int e0 = rs[r], e1 = rs[r + 1];
        float agg = 0.f;
        for (int e = e0; e < e1; e += 8) {
            int cc[8];
            float vv[8];
#pragma unroll
            for (int j = 0; j < 8; ++j) {
                int ee = e + j;
                cc[j] = scol[ee < e1 ? ee : e1 - 1];
            }
#pragma unroll
            for (int j = 0; j < 8; ++j) {
                float v = b2f(g[(size_t)cc[j] * HID + lane]);
                vv[j] = (e + j < e1) ? v : 0.f;
            }
            agg += ((vv[0] + vv[1]) + (vv[2] + vv[3])) +
                   ((vv[4] + vv[5]) + (vv[6] + vv[7]));
        }
        sout[(size_t)r * HID + lane] =
            (1.f - ALPHA) * dinv[r] * agg + ALPHA * x0[(size_t)r * HID + lane];
    }
}

// h = (1-beta)*s + beta*(s@cw), in place; 4-way split FMA chains for ILP.
__global__ __launch_bounds__(256, 2) void dense_stats_kernel(float* __restrict__ s_in,
        const float* __restrict__ cw, float* __restrict__ stats, float beta, int n) {
    __shared__ float red[4 * 128];
    int wave = threadIdx.x >> 6, lane = threadIdx.x & 63;
    float w[HID];
#pragma unroll
    for (int k = 0; k < HID; ++k) w[k] = cw[k * HID + lane];
    float lsum = 0.f, lsq = 0.f;
    int nw = gridDim.x * 4;
    for (int r = blockIdx.x * 4 + wave; r < n; r += nw) {
        float sv = s_in[(size_t)r * HID + lane];
        float m0 = 0.f, m1 = 0.f, m2 = 0.f, m3 = 0.f;
#pragma unroll
        for (int k = 0; k < HID; k += 4) {
            m0 += __shfl(sv, k,     64) * w[k];
            m1 += __shfl(sv, k + 1, 64) * w[k + 1];
            m2 += __shfl(sv, k + 2, 64) * w[k + 2];
            m3 += __shfl(sv, k + 3, 64) * w[k + 3];
        }
        float m = (m0 + m1) + (m2 + m3);
        float hv = (1.f - beta) * sv + beta * m;
        s_in[(size_t)r * HID + lane] = hv;
        lsum += hv; lsq += hv * hv;
    }
    red[wave * 128 + lane] = lsum;
    red[wave * 128 + 64 + lane] = lsq;
    __syncthreads();
    if (threadIdx.x < 128) {
        int t = threadIdx.x;
        float v = red[t] + red[128 + t] + red[256 + t] + red[384 + t];
        atomicAdd(&stats[t], v);
    }
}

// BN + residual + relu in place; also writes next-layer gather twin
__global__ void layerB_kernel(float4* __restrict__ h, const float4* __restrict__ xprev,
        const float* __restrict__ stats, const float* __restrict__ gamma,
        const float* __restrict__ bnb, const float* __restrict__ dinv,
        ushort4* __restrict__ g, int total4) {
    int i = blockIdx.x * blockDim.x + threadIdx.x;
    if (i >= total4) return;
    int fb = (i & 15) * 4;
    int row = i >> 4;
    float dr = dinv[row];
    float4 hv = h[i];
    float4 xp = xprev[i];
    float o[4];
    float hin[4] = { hv.x, hv.y, hv.z, hv.w };
    float xin[4] = { xp.x, xp.y, xp.z, xp.w };
#pragma unroll
    for (int j = 0; j < 4; ++j) {
        int f = fb + j;
        float mu = stats[f] * (1.0f / N_NODES);
        float var = stats[64 + f] * (1.0f / N_NODES) - mu * mu;
        if (var < 0.f) var = 0.f;
        float inv = rsqrtf(var + BN_EPS);
        float v = (hin[j] - mu) * inv * gamma[f] + bnb[f] + xin[j];
        o[j] = v > 0.f ? v : 0.f;
    }
    h[i] = make_float4(o[0], o[1], o[2], o[3]);
    ushort4 gu;
    gu.x = f2b(dr * o[0]); gu.y = f2b(dr * o[1]);
    gu.z = f2b(dr * o[2]); gu.w = f2b(dr * o[3]);
    g[i] = gu;
}

// out = x @ W1 + b1; 4-way split FMA chains
__global__ __launch_bounds__(256, 2) void final_kernel(const float* __restrict__ xcur,
        const float* __restrict__ W1, const float* __restrict__ b1,
        float* __restrict__ out, int n) {
    int wave = threadIdx.x >> 6, lane = threadIdx.x & 63;
    float w[HID];
#pragma unroll
    for (int k = 0; k < HID; ++k) w[k] = W1[k * OUT_F + lane];
    float bias = b1[lane];
    int nw = gridDim.x * 4;
    for (int r = blockIdx.x * 4 + wave; r < n; r += nw) {
        float xv = xcur[(size_t)r * HID + lane];
        float m0 = bias, m1 = 0.f, m2 = 0.f, m3 = 0.f;
#pragma unroll
        for (int k = 0; k < HID; k += 4) {
            m0 += __shfl(xv, k,     64) * w[k];
            m1 += __shfl(xv, k + 1, 64) * w[k + 1];
            m2 += __shfl(xv, k + 2, 64) * w[k + 2];
            m3 += __shfl(xv, k + 3, 64) * w[k + 3];
        }
        out[(size_t)r * OUT_F + lane] = (m0 + m1) + (m2 + m3);
    }
}

extern "C" void kernel_launch(void* const* d_in, const int* in_sizes, int n_in,
                              void* d_out, int out_size, void* d_ws, size_t ws_size,
                              hipStream_t stream) {
    const float* x     = (const float*)d_in[0];
    const int*   edges = (const int*)d_in[1];
    const float* W0    = (const float*)d_in[2];
    const float* b0    = (const float*)d_in[3];
    const float* cw    = (const float*)d_in[4];
    const float* gamma = (const float*)d_in[5];
    const float* bnb   = (const float*)d_in[6];
    const float* W1    = (const float*)d_in[7];
    const float* b1    = (const float*)d_in[8];
    float* out = (float*)d_out;

    char* ws = (char*)d_ws;
    float* x0    = (float*)(ws + OFF_X0);
    float* bufA  = (float*)(ws + OFF_HA);
    float* bufB  = (float*)(ws + OFF_HB);
    unsigned short* gbuf = (unsigned short*)(ws + OFF_GB);
    int*   scol  = (int*)(ws + OFF_SORTED);
    int*   cnt   = (int*)(ws + OFF_CNT);
    float* stats = (float*)(ws + OFF_STATS);
    float* dinv  = (float*)(ws + OFF_DINV);
    int*   rs    = (int*)(ws + OFF_ROWSTART);
    int*   cur   = (int*)(ws + OFF_CURSOR);
    int*   bsum  = (int*)(ws + OFF_BSUM);

    hipMemsetAsync(ws + ZERO_OFF, 0, ZERO_BYTES, stream);
    hist_kernel<<<(N_EDGES + 255) / 256, 256, 0, stream>>>(edges, cnt, N_EDGES);
    dinv_kernel<<<(N_NODES + 255) / 256, 256, 0, stream>>>(cnt, dinv, N_NODES);
    blocksum_kernel<<<NSCAN_BLOCKS, SCAN_BLK, 0, stream>>>(cnt, bsum, N_NODES);
    scan_bsum_kernel<<<1, 512, 0, stream>>>(bsum, NSCAN_BLOCKS);
    scan_write_kernel<<<NSCAN_BLOCKS, SCAN_BLK, 0, stream>>>(cnt, bsum, rs, cur, N_NODES);
    scatter_kernel<<<(N_EDGES + 255) / 256, 256, 0, stream>>>(edges, cur, scol, N_EDGES);
    fc0_kernel<<<2048, 256, 0, stream>>>(x, W0, b0, dinv, x0, gbuf, N_NODES);

    const float* xc = x0;
    float* bufs[2] = { bufA, bufB };
    for (int i = 0; i < NLAYERS; ++i) {
        float beta = logf(0.5f / (float)(i + 1) + 1.0f);
        float* hb = bufs[i & 1];
        spmm_kernel<<<2048, 256, 0, stream>>>(gbuf, x0, dinv, rs, scol, hb, N_NODES);
        dense_stats_kernel<<<2048, 256, 0, stream>>>(hb,
                cw + (size_t)i * HID * HID, stats + i * 128, beta, N_NODES);
        layerB_kernel<<<(N_NODES * HID / 4 + 255) / 256, 256, 0, stream>>>(
                (float4*)hb, (const float4*)xc,
                stats + i * 128, gamma + i * HID, bnb + i * HID, dinv,
                (ushort4*)gbuf, N_NODES * HID / 4);
        xc = hb;
    }
    final_kernel<<<2048, 256, 0, stream>>>(xc, W1, b1, out, N_NODES);
}

// Round 8
// 900.152 us; speedup vs baseline: 1.0606x; 1.0533x over previous
//
#include <hip/hip_runtime.h>
#include <math.h>

#define N_NODES 100000
#define N_EDGES 1000000
#define IN_F 128
#define HID 64
#define OUT_F 64
#define NLAYERS 4
#define ALPHA 0.1f
#define BN_EPS 1e-5f

#define SCAN_BLK 256
#define NSCAN_BLOCKS ((N_NODES + SCAN_BLK - 1) / SCAN_BLK)   // 391

// ---- workspace layout (bytes) ----
static const size_t OFF_X0       = 0;                       // N*64*4 = 25600000
static const size_t OFF_HA       = 25600000;
static const size_t OFF_HB       = 51200000;
static const size_t OFF_GB       = 76800000;                // N*64*2 = 12800000 (bf16, dinv-prescaled)
static const size_t OFF_SORTED   = 89600000;                // E*4 = 4000000
static const size_t OFF_CNT      = 93600000;                // N*4
static const size_t OFF_STATS    = 94000000;                // 512*4 = 2048
static const size_t OFF_DINV     = 94002048;                // N*4
static const size_t OFF_ROWSTART = 94402048;                // (N+1)*4 -> 400016
static const size_t OFF_CURSOR   = 94802064;                // N*4
static const size_t OFF_BSUM     = 95202064;                // 391*4 -> pad 2048; end = 95204112
static const size_t ZERO_OFF     = OFF_CNT;
static const size_t ZERO_BYTES   = 402048;

__device__ __forceinline__ unsigned short f2b(float f) {
    unsigned int u = __float_as_uint(f);
    u += 0x7FFFu + ((u >> 16) & 1u);        // round-to-nearest-even
    return (unsigned short)(u >> 16);
}
__device__ __forceinline__ float b2f(unsigned short h) {
    return __uint_as_float(((unsigned int)h) << 16);
}

__global__ void hist_kernel(const int* __restrict__ row, int* __restrict__ cnt, int e) {
    int i = blockIdx.x * blockDim.x + threadIdx.x;
    if (i < e) atomicAdd(&cnt[row[i]], 1);
}

__global__ void dinv_kernel(const int* __restrict__ cnt, float* __restrict__ dinv, int n) {
    int i = blockIdx.x * blockDim.x + threadIdx.x;
    if (i < n) {
        int d = cnt[i];
        dinv[i] = d > 0 ? rsqrtf((float)d) : 0.0f;
    }
}

// ---- 3-phase multi-block exclusive scan of cnt -> rs[0..n], cur ----
__global__ __launch_bounds__(SCAN_BLK) void blocksum_kernel(const int* __restrict__ cnt,
        int* __restrict__ bsum, int n) {
    __shared__ int red[SCAN_BLK / 64];
    int i = blockIdx.x * SCAN_BLK + threadIdx.x;
    int v = (i < n) ? cnt[i] : 0;
#pragma unroll
    for (int off = 32; off > 0; off >>= 1) v += __shfl_down(v, off, 64);
    if ((threadIdx.x & 63) == 0) red[threadIdx.x >> 6] = v;
    __syncthreads();
    if (threadIdx.x == 0) {
        int s = 0;
#pragma unroll
        for (int j = 0; j < SCAN_BLK / 64; ++j) s += red[j];
        bsum[blockIdx.x] = s;
    }
}

__global__ __launch_bounds__(512) void scan_bsum_kernel(int* __restrict__ bsum, int nb) {
    __shared__ int lds[512];
    int t = threadIdx.x;
    lds[t] = (t < nb) ? bsum[t] : 0;
    __syncthreads();
    for (int off = 1; off < 512; off <<= 1) {
        int v = lds[t];
        int add = (t >= off) ? lds[t - off] : 0;
        __syncthreads();
        lds[t] = v + add;
        __syncthreads();
    }
    if (t < nb) bsum[t] = (t == 0) ? 0 : lds[t - 1];
}

__global__ __launch_bounds__(SCAN_BLK) void scan_write_kernel(const int* __restrict__ cnt,
        const int* __restrict__ bsum, int* __restrict__ rs, int* __restrict__ cur, int n) {
    __shared__ int lds[SCAN_BLK];
    int t = threadIdx.x;
    int i = blockIdx.x * SCAN_BLK + t;
    int c = (i < n) ? cnt[i] : 0;
    lds[t] = c;
    __syncthreads();
    for (int off = 1; off < SCAN_BLK; off <<= 1) {
        int v = lds[t];
        int add = (t >= off) ? lds[t - off] : 0;
        __syncthreads();
        lds[t] = v + add;
        __syncthreads();
    }
    if (i < n) {
        int excl = bsum[blockIdx.x] + lds[t] - c;
        rs[i] = excl;
        cur[i] = excl;
        if (i == n - 1) rs[n] = excl + c;
    }
}

__global__ void scatter_kernel(const int* __restrict__ edges, int* __restrict__ cur,
                               int* __restrict__ scol, int e) {
    int i = blockIdx.x * blockDim.x + threadIdx.x;
    if (i < e) {
        int r = edges[i];
        int c = edges[e + i];
        int pos = atomicAdd(&cur[r], 1);
        scol[pos] = c;
    }
}

// x0 = relu(x @ W0 + b0) + bf16 gather twin. Split-K across wave pairs.
// Broadcast of the x row via wave-uniform float4 VMEM reads (L1 broadcast,
// 4 k per instr) instead of ds_bpermute — keeps the per-CU LDS pipe free.
__global__ __launch_bounds__(256, 2) void fc0_kernel(const float* __restrict__ x,
        const float* __restrict__ W0, const float* __restrict__ b0,
        const float* __restrict__ dinv, float* __restrict__ out,
        unsigned short* __restrict__ g, int n) {
    __shared__ float part[2][4][2][64];     // [pb][wave][rowj][lane]
    int wave = threadIdx.x >> 6, lane = threadIdx.x & 63;
    int pairid = wave >> 1;      // which 2-row group (0 or 1)
    int half = wave & 1;         // which K-half this wave owns
    float w[64];
#pragma unroll
    for (int k = 0; k < 64; ++k) w[k] = W0[(half * 64 + k) * HID + lane];
    float bias = b0[lane];
    int stride = gridDim.x * 4;
    int pb = 0;
    for (int base = blockIdx.x * 4; base < n; base += stride, pb ^= 1) {
        int r0 = base + pairid * 2;
        float m[2];
#pragma unroll
        for (int j = 0; j < 2; ++j) {
            int r = r0 + j;
            const float4* xr = (const float4*)(x +
                    (size_t)(r < n ? r : n - 1) * IN_F + half * 64);
            float a0 = 0.f, a1 = 0.f, a2 = 0.f, a3 = 0.f;
#pragma unroll
            for (int kk = 0; kk < 16; ++kk) {
                float4 c = xr[kk];
                a0 += c.x * w[4 * kk];
                a1 += c.y * w[4 * kk + 1];
                a2 += c.z * w[4 * kk + 2];
                a3 += c.w * w[4 * kk + 3];
            }
            m[j] = (a0 + a1) + (a2 + a3);
        }
        part[pb][wave][0][lane] = m[0];
        part[pb][wave][1][lane] = m[1];
        __syncthreads();
        if (half == 0) {
#pragma unroll
            for (int j = 0; j < 2; ++j) {
                int r = r0 + j;
                if (r < n) {
                    float v = m[j] + part[pb][wave + 1][j][lane] + bias;
                    v = v > 0.f ? v : 0.f;
                    out[(size_t)r * HID + lane] = v;
                    g[(size_t)r * HID + lane] = f2b(dinv[r] * v);
                }
            }
        }
    }
}

// SPMM from bf16 dinv-prescaled gather buffer: one 128B line per edge.
__global__ __launch_bounds__(256, 8) void spmm_kernel(const unsigned short* __restrict__ g,
        const float* __restrict__ x0, const float* __restrict__ dinv,
        const int* __restrict__ rs, const int* __restrict__ scol,
        float* __restrict__ sout, int n) {
    int wave = threadIdx.x >> 6, lane = threadIdx.x & 63;
    int nw = gridDim.x * 4;
    for (int r = blockIdx.x * 4 + wave; r < n; r += nw) {
        int e0 = rs[r], e1 = rs[r + 1];
        float agg = 0.f;
        for (int e = e0; e < e1; e += 8) {
            int cc[8];
            float vv[8];
#pragma unroll
            for (int j = 0; j < 8; ++j) {
                int ee = e + j;
                cc[j] = scol[ee < e1 ? ee : e1 - 1];
            }
#pragma unroll
            for (int j = 0; j < 8; ++j) {
                float v = b2f(g[(size_t)cc[j] * HID + lane]);
                vv[j] = (e + j < e1) ? v : 0.f;
            }
            agg += ((vv[0] + vv[1]) + (vv[2] + vv[3])) +
                   ((vv[4] + vv[5]) + (vv[6] + vv[7]));
        }
        sout[(size_t)r * HID + lane] =
            (1.f - ALPHA) * dinv[r] * agg + ALPHA * x0[(size_t)r * HID + lane];
    }
}

// h = (1-beta)*s + beta*(s@cw), in place; broadcast via uniform float4 reads.
__global__ __launch_bounds__(256, 2) void dense_stats_kernel(float* __restrict__ s_in,
        const float* __restrict__ cw, float* __restrict__ stats, float beta, int n) {
    __shared__ float red[4 * 128];
    int wave = threadIdx.x >> 6, lane = threadIdx.x & 63;
    float w[HID];
#pragma unroll
    for (int k = 0; k < HID; ++k) w[k] = cw[k * HID + lane];
    float lsum = 0.f, lsq = 0.f;
    int nw = gridDim.x * 4;
    for (int r = blockIdx.x * 4 + wave; r < n; r += nw) {
        float sv = s_in[(size_t)r * HID + lane];
        const float4* srow = (const float4*)(s_in + (size_t)r * HID);
        float a0 = 0.f, a1 = 0.f, a2 = 0.f, a3 = 0.f;
#pragma unroll
        for (int kk = 0; kk < 16; ++kk) {
            float4 c = srow[kk];
            a0 += c.x * w[4 * kk];
            a1 += c.y * w[4 * kk + 1];
            a2 += c.z * w[4 * kk + 2];
            a3 += c.w * w[4 * kk + 3];
        }
        float m = (a0 + a1) + (a2 + a3);
        float hv = (1.f - beta) * sv + beta * m;
        s_in[(size_t)r * HID + lane] = hv;
        lsum += hv; lsq += hv * hv;
    }
    red[wave * 128 + lane] = lsum;
    red[wave * 128 + 64 + lane] = lsq;
    __syncthreads();
    if (threadIdx.x < 128) {
        int t = threadIdx.x;
        float v = red[t] + red[128 + t] + red[256 + t] + red[384 + t];
        atomicAdd(&stats[t], v);
    }
}

// BN + residual + relu in place; also writes next-layer gather twin
__global__ void layerB_kernel(float4* __restrict__ h, const float4* __restrict__ xprev,
        const float* __restrict__ stats, const float* __restrict__ gamma,
        const float* __restrict__ bnb, const float* __restrict__ dinv,
        ushort4* __restrict__ g, int total4) {
    int i = blockIdx.x * blockDim.x + threadIdx.x;
    if (i >= total4) return;
    int fb = (i & 15) * 4;
    int row = i >> 4;
    float dr = dinv[row];
    float4 hv = h[i];
    float4 xp = xprev[i];
    float o[4];
    float hin[4] = { hv.x, hv.y, hv.z, hv.w };
    float xin[4] = { xp.x, xp.y, xp.z, xp.w };
#pragma unroll
    for (int j = 0; j < 4; ++j) {
        int f = fb + j;
        float mu = stats[f] * (1.0f / N_NODES);
        float var = stats[64 + f] * (1.0f / N_NODES) - mu * mu;
        if (var < 0.f) var = 0.f;
        float inv = rsqrtf(var + BN_EPS);
        float v = (hin[j] - mu) * inv * gamma[f] + bnb[f] + xin[j];
        o[j] = v > 0.f ? v : 0.f;
    }
    h[i] = make_float4(o[0], o[1], o[2], o[3]);
    ushort4 gu;
    gu.x = f2b(dr * o[0]); gu.y = f2b(dr * o[1]);
    gu.z = f2b(dr * o[2]); gu.w = f2b(dr * o[3]);
    g[i] = gu;
}

// out = x @ W1 + b1; broadcast via uniform float4 reads
__global__ __launch_bounds__(256, 2) void final_kernel(const float* __restrict__ xcur,
        const float* __restrict__ W1, const float* __restrict__ b1,
        float* __restrict__ out, int n) {
    int wave = threadIdx.x >> 6, lane = threadIdx.x & 63;
    float w[HID];
#pragma unroll
    for (int k = 0; k < HID; ++k) w[k] = W1[k * OUT_F + lane];
    float bias = b1[lane];
    int nw = gridDim.x * 4;
    for (int r = blockIdx.x * 4 + wave; r < n; r += nw) {
        const float4* xr = (const float4*)(xcur + (size_t)r * HID);
        float a0 = bias, a1 = 0.f, a2 = 0.f, a3 = 0.f;
#pragma unroll
        for (int kk = 0; kk < 16; ++kk) {
            float4 c = xr[kk];
            a0 += c.x * w[4 * kk];
            a1 += c.y * w[4 * kk + 1];
            a2 += c.z * w[4 * kk + 2];
            a3 += c.w * w[4 * kk + 3];
        }
        out[(size_t)r * OUT_F + lane] = (a0 + a1) + (a2 + a3);
    }
}

extern "C" void kernel_launch(void* const* d_in, const int* in_sizes, int n_in,
                              void* d_out, int out_size, void* d_ws, size_t ws_size,
                              hipStream_t stream) {
    const float* x     = (const float*)d_in[0];
    const int*   edges = (const int*)d_in[1];
    const float* W0    = (const float*)d_in[2];
    const float* b0    = (const float*)d_in[3];
    const float* cw    = (const float*)d_in[4];
    const float* gamma = (const float*)d_in[5];
    const float* bnb   = (const float*)d_in[6];
    const float* W1    = (const float*)d_in[7];
    const float* b1    = (const float*)d_in[8];
    float* out = (float*)d_out;

    char* ws = (char*)d_ws;
    float* x0    = (float*)(ws + OFF_X0);
    float* bufA  = (float*)(ws + OFF_HA);
    float* bufB  = (float*)(ws + OFF_HB);
    unsigned short* gbuf = (unsigned short*)(ws + OFF_GB);
    int*   scol  = (int*)(ws + OFF_SORTED);
    int*   cnt   = (int*)(ws + OFF_CNT);
    float* stats = (float*)(ws + OFF_STATS);
    float* dinv  = (float*)(ws + OFF_DINV);
    int*   rs    = (int*)(ws + OFF_ROWSTART);
    int*   cur   = (int*)(ws + OFF_CURSOR);
    int*   bsum  = (int*)(ws + OFF_BSUM);

    hipMemsetAsync(ws + ZERO_OFF, 0, ZERO_BYTES, stream);
    hist_kernel<<<(N_EDGES + 255) / 256, 256, 0, stream>>>(edges, cnt, N_EDGES);
    dinv_kernel<<<(N_NODES + 255) / 256, 256, 0, stream>>>(cnt, dinv, N_NODES);
    blocksum_kernel<<<NSCAN_BLOCKS, SCAN_BLK, 0, stream>>>(cnt, bsum, N_NODES);
    scan_bsum_kernel<<<1, 512, 0, stream>>>(bsum, NSCAN_BLOCKS);
    scan_write_kernel<<<NSCAN_BLOCKS, SCAN_BLK, 0, stream>>>(cnt, bsum, rs, cur, N_NODES);
    scatter_kernel<<<(N_EDGES + 255) / 256, 256, 0, stream>>>(edges, cur, scol, N_EDGES);
    fc0_kernel<<<2048, 256, 0, stream>>>(x, W0, b0, dinv, x0, gbuf, N_NODES);

    const float* xc = x0;
    float* bufs[2] = { bufA, bufB };
    for (int i = 0; i < NLAYERS; ++i) {
        float beta = logf(0.5f / (float)(i + 1) + 1.0f);
        float* hb = bufs[i & 1];
        spmm_kernel<<<2048, 256, 0, stream>>>(gbuf, x0, dinv, rs, scol, hb, N_NODES);
        dense_stats_kernel<<<2048, 256, 0, stream>>>(hb,
                cw + (size_t)i * HID * HID, stats + i * 128, beta, N_NODES);
        layerB_kernel<<<(N_NODES * HID / 4 + 255) / 256, 256, 0, stream>>>(
                (float4*)hb, (const float4*)xc,
                stats + i * 128, gamma + i * HID, bnb + i * HID, dinv,
                (ushort4*)gbuf, N_NODES * HID / 4);
        xc = hb;
    }
    final_kernel<<<2048, 256, 0, stream>>>(xc, W1, b1, out, N_NODES);
}

// Round 9
// 808.232 us; speedup vs baseline: 1.1813x; 1.1137x over previous
//
#include <hip/hip_runtime.h>
#include <math.h>

#define N_NODES 100000
#define N_EDGES 1000000
#define IN_F 128
#define HID 64
#define OUT_F 64
#define NLAYERS 4
#define ALPHA 0.1f
#define BN_EPS 1e-5f

#define SCAN_BLK 256
#define NSCAN_BLOCKS ((N_NODES + SCAN_BLK - 1) / SCAN_BLK)   // 391

// ---- workspace layout (bytes) ----
static const size_t OFF_X0       = 0;                       // N*64*4 = 25600000
static const size_t OFF_HA       = 25600000;
static const size_t OFF_HB       = 51200000;
static const size_t OFF_GB       = 76800000;                // N*64*2 = 12800000 (bf16, dinv-prescaled)
static const size_t OFF_SORTED   = 89600000;                // E*4 = 4000000
static const size_t OFF_CNT      = 93600000;                // N*4
static const size_t OFF_STATS    = 94000000;                // 512*4 = 2048
static const size_t OFF_DINV     = 94002048;                // N*4
static const size_t OFF_ROWSTART = 94402048;                // (N+1)*4 -> 400016
static const size_t OFF_CURSOR   = 94802064;                // N*4
static const size_t OFF_BSUM     = 95202064;                // 391*4 -> pad 2048; end = 95204112
static const size_t ZERO_OFF     = OFF_CNT;
static const size_t ZERO_BYTES   = 402048;

__device__ __forceinline__ unsigned short f2b(float f) {
    unsigned int u = __float_as_uint(f);
    u += 0x7FFFu + ((u >> 16) & 1u);        // round-to-nearest-even
    return (unsigned short)(u >> 16);
}
__device__ __forceinline__ float b2f(unsigned short h) {
    return __uint_as_float(((unsigned int)h) << 16);
}

__global__ void hist_kernel(const int* __restrict__ row, int* __restrict__ cnt, int e) {
    int i = blockIdx.x * blockDim.x + threadIdx.x;
    if (i < e) atomicAdd(&cnt[row[i]], 1);
}

__global__ void dinv_kernel(const int* __restrict__ cnt, float* __restrict__ dinv, int n) {
    int i = blockIdx.x * blockDim.x + threadIdx.x;
    if (i < n) {
        int d = cnt[i];
        dinv[i] = d > 0 ? rsqrtf((float)d) : 0.0f;
    }
}

// ---- 3-phase multi-block exclusive scan of cnt -> rs[0..n], cur ----
__global__ __launch_bounds__(SCAN_BLK) void blocksum_kernel(const int* __restrict__ cnt,
        int* __restrict__ bsum, int n) {
    __shared__ int red[SCAN_BLK / 64];
    int i = blockIdx.x * SCAN_BLK + threadIdx.x;
    int v = (i < n) ? cnt[i] : 0;
#pragma unroll
    for (int off = 32; off > 0; off >>= 1) v += __shfl_down(v, off, 64);
    if ((threadIdx.x & 63) == 0) red[threadIdx.x >> 6] = v;
    __syncthreads();
    if (threadIdx.x == 0) {
        int s = 0;
#pragma unroll
        for (int j = 0; j < SCAN_BLK / 64; ++j) s += red[j];
        bsum[blockIdx.x] = s;
    }
}

__global__ __launch_bounds__(512) void scan_bsum_kernel(int* __restrict__ bsum, int nb) {
    __shared__ int lds[512];
    int t = threadIdx.x;
    lds[t] = (t < nb) ? bsum[t] : 0;
    __syncthreads();
    for (int off = 1; off < 512; off <<= 1) {
        int v = lds[t];
        int add = (t >= off) ? lds[t - off] : 0;
        __syncthreads();
        lds[t] = v + add;
        __syncthreads();
    }
    if (t < nb) bsum[t] = (t == 0) ? 0 : lds[t - 1];
}

__global__ __launch_bounds__(SCAN_BLK) void scan_write_kernel(const int* __restrict__ cnt,
        const int* __restrict__ bsum, int* __restrict__ rs, int* __restrict__ cur, int n) {
    __shared__ int lds[SCAN_BLK];
    int t = threadIdx.x;
    int i = blockIdx.x * SCAN_BLK + t;
    int c = (i < n) ? cnt[i] : 0;
    lds[t] = c;
    __syncthreads();
    for (int off = 1; off < SCAN_BLK; off <<= 1) {
        int v = lds[t];
        int add = (t >= off) ? lds[t - off] : 0;
        __syncthreads();
        lds[t] = v + add;
        __syncthreads();
    }
    if (i < n) {
        int excl = bsum[blockIdx.x] + lds[t] - c;
        rs[i] = excl;
        cur[i] = excl;
        if (i == n - 1) rs[n] = excl + c;
    }
}

__global__ void scatter_kernel(const int* __restrict__ edges, int* __restrict__ cur,
                               int* __restrict__ scol, int e) {
    int i = blockIdx.x * blockDim.x + threadIdx.x;
    if (i < e) {
        int r = edges[i];
        int c = edges[e + i];
        int pos = atomicAdd(&cur[r], 1);
        scol[pos] = c;
    }
}

// fc0 as classic LDS-tiled fp32 GEMM: [N,128]@[128,64] + bias, relu, bf16 twin.
// 64-row x 64-col tile per block, K chunks of 64; thread = 4x4 sub-tile.
// Staging = per-lane coalesced float4 (1KB/wave-instr); compute = ds_read_b128.
__global__ __launch_bounds__(256, 4) void fc0_kernel(const float* __restrict__ x,
        const float* __restrict__ W0, const float* __restrict__ b0,
        const float* __restrict__ dinv, float* __restrict__ out,
        unsigned short* __restrict__ g, int n) {
    __shared__ float At[64][68];   // x^T slice: At[k][r]
    __shared__ float Bt[64][68];   // W0 slice:  Bt[k][c]
    int t = threadIdx.x;
    int base = blockIdx.x * 64;
    int tx = t & 15, ty = t >> 4;
    int r0 = ty * 4, c0 = tx * 4;
    float acc[4][4] = {{0.f}};
    for (int kc = 0; kc < IN_F; kc += 64) {
        __syncthreads();
#pragma unroll
        for (int i = 0; i < 4; ++i) {           // stage x tile (64 rows x 64 k)
            int idx = (i * 256 + t) * 4;
            int r = idx >> 6, kk = idx & 63;
            int rr = base + r; if (rr >= n) rr = n - 1;
            float4 v = *(const float4*)(x + (size_t)rr * IN_F + kc + kk);
            At[kk][r] = v.x; At[kk + 1][r] = v.y; At[kk + 2][r] = v.z; At[kk + 3][r] = v.w;
        }
#pragma unroll
        for (int i = 0; i < 4; ++i) {           // stage W0 slice (64 k x 64 c)
            int idx = (i * 256 + t) * 4;
            int k = idx >> 6, c = idx & 63;
            float4 v = *(const float4*)(W0 + (size_t)(kc + k) * HID + c);
            Bt[k][c] = v.x; Bt[k][c + 1] = v.y; Bt[k][c + 2] = v.z; Bt[k][c + 3] = v.w;
        }
        __syncthreads();
#pragma unroll 4
        for (int k = 0; k < 64; ++k) {
            float4 a = *(const float4*)&At[k][r0];
            float4 b = *(const float4*)&Bt[k][c0];
            acc[0][0] += a.x * b.x; acc[0][1] += a.x * b.y; acc[0][2] += a.x * b.z; acc[0][3] += a.x * b.w;
            acc[1][0] += a.y * b.x; acc[1][1] += a.y * b.y; acc[1][2] += a.y * b.z; acc[1][3] += a.y * b.w;
            acc[2][0] += a.z * b.x; acc[2][1] += a.z * b.y; acc[2][2] += a.z * b.z; acc[2][3] += a.z * b.w;
            acc[3][0] += a.w * b.x; acc[3][1] += a.w * b.y; acc[3][2] += a.w * b.z; acc[3][3] += a.w * b.w;
        }
    }
    float4 bias = *(const float4*)(b0 + c0);
#pragma unroll
    for (int i = 0; i < 4; ++i) {
        int r = base + r0 + i;
        if (r < n) {
            float v0 = acc[i][0] + bias.x; v0 = v0 > 0.f ? v0 : 0.f;
            float v1 = acc[i][1] + bias.y; v1 = v1 > 0.f ? v1 : 0.f;
            float v2 = acc[i][2] + bias.z; v2 = v2 > 0.f ? v2 : 0.f;
            float v3 = acc[i][3] + bias.w; v3 = v3 > 0.f ? v3 : 0.f;
            *(float4*)(out + (size_t)r * HID + c0) = make_float4(v0, v1, v2, v3);
            float dr = dinv[r];
            ushort4 gu;
            gu.x = f2b(dr * v0); gu.y = f2b(dr * v1);
            gu.z = f2b(dr * v2); gu.w = f2b(dr * v3);
            *(ushort4*)(g + (size_t)r * HID + c0) = gu;
        }
    }
}

// SPMM from bf16 dinv-prescaled gather buffer: one 128B line per edge.
__global__ __launch_bounds__(256, 8) void spmm_kernel(const unsigned short* __restrict__ g,
        const float* __restrict__ x0, const float* __restrict__ dinv,
        const int* __restrict__ rs, const int* __restrict__ scol,
        float* __restrict__ sout, int n) {
    int wave = threadIdx.x >> 6, lane = threadIdx.x & 63;
    int nw = gridDim.x * 4;
    for (int r = blockIdx.x * 4 + wave; r < n; r += nw) {
        int e0 = rs[r], e1 = rs[r + 1];
        float agg = 0.f;
        for (int e = e0; e < e1; e += 8) {
            int cc[8];
            float vv[8];
#pragma unroll
            for (int j = 0; j < 8; ++j) {
                int ee = e + j;
                cc[j] = scol[ee < e1 ? ee : e1 - 1];
            }
#pragma unroll
            for (int j = 0; j < 8; ++j) {
                float v = b2f(g[(size_t)cc[j] * HID + lane]);
                vv[j] = (e + j < e1) ? v : 0.f;
            }
            agg += ((vv[0] + vv[1]) + (vv[2] + vv[3])) +
                   ((vv[4] + vv[5]) + (vv[6] + vv[7]));
        }
        sout[(size_t)r * HID + lane] =
            (1.f - ALPHA) * dinv[r] * agg + ALPHA * x0[(size_t)r * HID + lane];
    }
}

// h = (1-beta)*s + beta*(s@cw), in place; broadcast via uniform float4 reads.
__global__ __launch_bounds__(256, 2) void dense_stats_kernel(float* __restrict__ s_in,
        const float* __restrict__ cw, float* __restrict__ stats, float beta, int n) {
    __shared__ float red[4 * 128];
    int wave = threadIdx.x >> 6, lane = threadIdx.x & 63;
    float w[HID];
#pragma unroll
    for (int k = 0; k < HID; ++k) w[k] = cw[k * HID + lane];
    float lsum = 0.f, lsq = 0.f;
    int nw = gridDim.x * 4;
    for (int r = blockIdx.x * 4 + wave; r < n; r += nw) {
        float sv = s_in[(size_t)r * HID + lane];
        const float4* srow = (const float4*)(s_in + (size_t)r * HID);
        float a0 = 0.f, a1 = 0.f, a2 = 0.f, a3 = 0.f;
#pragma unroll
        for (int kk = 0; kk < 16; ++kk) {
            float4 c = srow[kk];
            a0 += c.x * w[4 * kk];
            a1 += c.y * w[4 * kk + 1];
            a2 += c.z * w[4 * kk + 2];
            a3 += c.w * w[4 * kk + 3];
        }
        float m = (a0 + a1) + (a2 + a3);
        float hv = (1.f - beta) * sv + beta * m;
        s_in[(size_t)r * HID + lane] = hv;
        lsum += hv; lsq += hv * hv;
    }
    red[wave * 128 + lane] = lsum;
    red[wave * 128 + 64 + lane] = lsq;
    __syncthreads();
    if (threadIdx.x < 128) {
        int t = threadIdx.x;
        float v = red[t] + red[128 + t] + red[256 + t] + red[384 + t];
        atomicAdd(&stats[t], v);
    }
}

// BN + residual + relu in place; also writes next-layer gather twin
__global__ void layerB_kernel(float4* __restrict__ h, const float4* __restrict__ xprev,
        const float* __restrict__ stats, const float* __restrict__ gamma,
        const float* __restrict__ bnb, const float* __restrict__ dinv,
        ushort4* __restrict__ g, int total4) {
    int i = blockIdx.x * blockDim.x + threadIdx.x;
    if (i >= total4) return;
    int fb = (i & 15) * 4;
    int row = i >> 4;
    float dr = dinv[row];
    float4 hv = h[i];
    float4 xp = xprev[i];
    float o[4];
    float hin[4] = { hv.x, hv.y, hv.z, hv.w };
    float xin[4] = { xp.x, xp.y, xp.z, xp.w };
#pragma unroll
    for (int j = 0; j < 4; ++j) {
        int f = fb + j;
        float mu = stats[f] * (1.0f / N_NODES);
        float var = stats[64 + f] * (1.0f / N_NODES) - mu * mu;
        if (var < 0.f) var = 0.f;
        float inv = rsqrtf(var + BN_EPS);
        float v = (hin[j] - mu) * inv * gamma[f] + bnb[f] + xin[j];
        o[j] = v > 0.f ? v : 0.f;
    }
    h[i] = make_float4(o[0], o[1], o[2], o[3]);
    ushort4 gu;
    gu.x = f2b(dr * o[0]); gu.y = f2b(dr * o[1]);
    gu.z = f2b(dr * o[2]); gu.w = f2b(dr * o[3]);
    g[i] = gu;
}

// out = x @ W1 + b1; broadcast via uniform float4 reads
__global__ __launch_bounds__(256, 2) void final_kernel(const float* __restrict__ xcur,
        const float* __restrict__ W1, const float* __restrict__ b1,
        float* __restrict__ out, int n) {
    int wave = threadIdx.x >> 6, lane = threadIdx.x & 63;
    float w[HID];
#pragma unroll
    for (int k = 0; k < HID; ++k) w[k] = W1[k * OUT_F + lane];
    float bias = b1[lane];
    int nw = gridDim.x * 4;
    for (int r = blockIdx.x * 4 + wave; r < n; r += nw) {
        const float4* xr = (const float4*)(xcur + (size_t)r * HID);
        float a0 = bias, a1 = 0.f, a2 = 0.f, a3 = 0.f;
#pragma unroll
        for (int kk = 0; kk < 16; ++kk) {
            float4 c = xr[kk];
            a0 += c.x * w[4 * kk];
            a1 += c.y * w[4 * kk + 1];
            a2 += c.z * w[4 * kk + 2];
            a3 += c.w * w[4 * kk + 3];
        }
        out[(size_t)r * OUT_F + lane] = (a0 + a1) + (a2 + a3);
    }
}

extern "C" void kernel_launch(void* const* d_in, const int* in_sizes, int n_in,
                              void* d_out, int out_size, void* d_ws, size_t ws_size,
                              hipStream_t stream) {
    const float* x     = (const float*)d_in[0];
    const int*   edges = (const int*)d_in[1];
    const float* W0    = (const float*)d_in[2];
    const float* b0    = (const float*)d_in[3];
    const float* cw    = (const float*)d_in[4];
    const float* gamma = (const float*)d_in[5];
    const float* bnb   = (const float*)d_in[6];
    const float* W1    = (const float*)d_in[7];
    const float* b1    = (const float*)d_in[8];
    float* out = (float*)d_out;

    char* ws = (char*)d_ws;
    float* x0    = (float*)(ws + OFF_X0);
    float* bufA  = (float*)(ws + OFF_HA);
    float* bufB  = (float*)(ws + OFF_HB);
    unsigned short* gbuf = (unsigned short*)(ws + OFF_GB);
    int*   scol  = (int*)(ws + OFF_SORTED);
    int*   cnt   = (int*)(ws + OFF_CNT);
    float* stats = (float*)(ws + OFF_STATS);
    float* dinv  = (float*)(ws + OFF_DINV);
    int*   rs    = (int*)(ws + OFF_ROWSTART);
    int*   cur   = (int*)(ws + OFF_CURSOR);
    int*   bsum  = (int*)(ws + OFF_BSUM);

    hipMemsetAsync(ws + ZERO_OFF, 0, ZERO_BYTES, stream);
    hist_kernel<<<(N_EDGES + 255) / 256, 256, 0, stream>>>(edges, cnt, N_EDGES);
    dinv_kernel<<<(N_NODES + 255) / 256, 256, 0, stream>>>(cnt, dinv, N_NODES);
    blocksum_kernel<<<NSCAN_BLOCKS, SCAN_BLK, 0, stream>>>(cnt, bsum, N_NODES);
    scan_bsum_kernel<<<1, 512, 0, stream>>>(bsum, NSCAN_BLOCKS);
    scan_write_kernel<<<NSCAN_BLOCKS, SCAN_BLK, 0, stream>>>(cnt, bsum, rs, cur, N_NODES);
    scatter_kernel<<<(N_EDGES + 255) / 256, 256, 0, stream>>>(edges, cur, scol, N_EDGES);
    fc0_kernel<<<(N_NODES + 63) / 64, 256, 0, stream>>>(x, W0, b0, dinv, x0, gbuf, N_NODES);

    const float* xc = x0;
    float* bufs[2] = { bufA, bufB };
    for (int i = 0; i < NLAYERS; ++i) {
        float beta = logf(0.5f / (float)(i + 1) + 1.0f);
        float* hb = bufs[i & 1];
        spmm_kernel<<<2048, 256, 0, stream>>>(gbuf, x0, dinv, rs, scol, hb, N_NODES);
        dense_stats_kernel<<<2048, 256, 0, stream>>>(hb,
                cw + (size_t)i * HID * HID, stats + i * 128, beta, N_NODES);
        layerB_kernel<<<(N_NODES * HID / 4 + 255) / 256, 256, 0, stream>>>(
                (float4*)hb, (const float4*)xc,
                stats + i * 128, gamma + i * HID, bnb + i * HID, dinv,
                (ushort4*)gbuf, N_NODES * HID / 4);
        xc = hb;
    }
    final_kernel<<<2048, 256, 0, stream>>>(xc, W1, b1, out, N_NODES);
}